// Round 4
// baseline (76.296 us; speedup 1.0000x reference)
//
#include <hip/hip_runtime.h>

// Problem constants (from reference setup_inputs)
#define B_    8
#define CIN   3
#define OC    16
#define HH    128
#define WW    128
#define KK    3
#define FF    27              // CIN*KK*KK
#define NSITE (B_*HH*WW)      // 131072 output pixel-sites
#define OGRP  4               // output channels per block
#define NGRP  (OC/OGRP)       // 4 channel groups
#define MBLK  512             // main-kernel block size
#define PH    130             // padded activation plane dim (128 + 1 halo each side)
#define PLANE (PH*PH)         // 16900 bytes per (b,c) plane
#define QA_ELEMS (B_*CIN*PLANE)        // 405600
#define T4_BYTES (NGRP*FF*256*4*2)     // 221184: 4 groups x 27 f x 256 a x 4ch x 2B
#define SLAB_INT4 (FF*256*4*2/16)      // 3456 dwordx4 chunks per 55296B group slab

// ---------------------------------------------------------------------------
// Prep kernel (single launch, no internal deps):
//  (1) qa: padded quantized activations [B][C][130][130]; border = 128 (qx=0).
//      Bit-exact vs reference: IEEE f32 divide + rintf (nearest-even, matches
//      jnp.round) + clip, then +128 bias to unsigned.
//  (2) T4: packed LUT slabs. T4[og][f][a] = 8-byte entry holding the four
//      int16 approx-products for output channels og*4..og*4+3 at activation
//      byte a. row = (a<<8)|iw, val = hi*256 + (lo&255) (fits int16).
// ---------------------------------------------------------------------------
__global__ void prep_kernel(const float* __restrict__ x,
                            const float* __restrict__ wgt,
                            const float* __restrict__ sx_p,
                            const float* __restrict__ sw_p,
                            const int*   __restrict__ lut,
                            short*       __restrict__ T4,
                            unsigned char* __restrict__ qa)
{
    const int i = blockIdx.x * blockDim.x + threadIdx.x;

    if (i < QA_ELEMS) {
        int bc = i / PLANE;            // b*CIN + c
        int p  = i - bc * PLANE;
        int hp = p / PH;               // padded row 0..129
        int wp = p - hp * PH;          // padded col 0..129
        int h  = hp - 1;
        int w  = wp - 1;
        unsigned char v = 128;         // zero-pad => qx=0 => a=128
        if ((unsigned)h < HH && (unsigned)w < WW) {
            float q = rintf(x[(bc * HH + h) * WW + w] / sx_p[0]);
            q = fminf(127.f, fmaxf(-127.f, q));
            v = (unsigned char)((int)q + 128);
        }
        qa[i] = v;
    }

    if (i < NGRP * FF * 256) {
        int og = i / (FF * 256);
        int r  = i - og * (FF * 256);
        int f  = r >> 8;
        int a  = r & 255;
        int vals[4];
        #pragma unroll
        for (int ol = 0; ol < 4; ++ol) {
            int o = og * OGRP + ol;
            float q = rintf(wgt[o * FF + f] / sw_p[0]);
            q = fminf(127.f, fmaxf(-127.f, q));
            int iw  = (int)q + 128;                  // in [1,255]
            int row = (a << 8) | iw;                 // reference idx = ip*256+iw
            int hi  = lut[2 * row];
            int lo  = lut[2 * row + 1] & 255;
            vals[ol] = hi * 256 + lo;                // [-32512, 32767]
        }
        int2 d;
        d.x = (vals[1] << 16) | (vals[0] & 0xffff);  // shorts [ch0, ch1]
        d.y = (vals[3] << 16) | (vals[2] & 0xffff);  // shorts [ch2, ch3]
        *reinterpret_cast<int2*>(T4 + (size_t)i * 4) = d;
    }
}

// ---------------------------------------------------------------------------
// Main kernel: block = (1024 sites, two 512-site passes) x (4 packed channels).
// Schedule (latency-overlap ordering):
//  1. issue BOTH passes' 54 patch ubyte loads (independent of LDS) so their
//     VMEM latency hides under the staging memcpy + barrier;
//  2. stage the group's 55296B T4 slab (7x dwordx4/thread, L2-resident src);
//  3. __syncthreads;
//  4. both passes' gathers interleaved: one ds_read_b64 per (pass,f), imm
//     offset f*2048; 54 independent DS ops in flight per thread.
// Superblocks (1024 sites) never cross a batch boundary, so pass 1 is the
// pass-0 address +4 padded rows. Outputs: nontemporal stores (write-once).
// 55296B LDS + VGPR<=128 (launch_bounds 512,4) -> 2 blocks/CU, 16 waves/CU.
// ---------------------------------------------------------------------------
__global__ __launch_bounds__(MBLK, 4) void conv_kernel(
    const unsigned char* __restrict__ qa,
    const short* __restrict__ T4,
    const float* __restrict__ bias,
    const float* __restrict__ sx_p,
    const float* __restrict__ sw_p,
    float*       __restrict__ out)
{
    __shared__ int2 colv[FF * 256];   // 55296 B: [f][a] -> 4 packed int16

    const int og  = blockIdx.x & 3;   // output-channel group
    const int sb2 = blockIdx.x >> 2;  // 1024-site superblock

    const int s0 = sb2 * 2 * MBLK + threadIdx.x;  // pass-0 site
    const int b  = s0 >> 14;                      // same b for both passes
    const int hw = s0 & 16383;
    const int h  = hw >> 7;
    const int w  = hw & 127;

    // ---- 1. issue both passes' patch loads (pass1 = +4 padded rows) ----
    int av0[FF], av1[FF];
    #pragma unroll
    for (int c = 0; c < CIN; ++c) {
        const unsigned char* __restrict__ bp =
            qa + (b * CIN + c) * PLANE + h * PH + w;
        #pragma unroll
        for (int kh = 0; kh < KK; ++kh)
            #pragma unroll
            for (int kw = 0; kw < KK; ++kw) {
                av0[c * 9 + kh * 3 + kw] = bp[kh * PH + kw];
                av1[c * 9 + kh * 3 + kw] = bp[(kh + 4) * PH + kw];
            }
    }

    // ---- 2. stage the group's packed slab: 3456 x 16B, <=7 per thread ----
    {
        const int4* __restrict__ src =
            reinterpret_cast<const int4*>(T4 + (size_t)og * FF * 256 * 4);
        int4* dst = reinterpret_cast<int4*>(colv);
        for (int c = threadIdx.x; c < SLAB_INT4; c += MBLK)
            dst[c] = src[c];
    }
    __syncthreads();

    // ---- 4. gathers, both passes interleaved ----
    int p0a = 0, p0b = 0, p0c = 0, p0d = 0;
    int p1a = 0, p1b = 0, p1c = 0, p1d = 0;
    #pragma unroll
    for (int f = 0; f < FF; ++f) {
        int2 d0 = colv[f * 256 + av0[f]];   // ds_read_b64, imm offset f*2048
        int2 d1 = colv[f * 256 + av1[f]];
        p0a += (short)d0.x;  p0b += d0.x >> 16;
        p0c += (short)d0.y;  p0d += d0.y >> 16;
        p1a += (short)d1.x;  p1b += d1.x >> 16;
        p1c += (short)d1.y;  p1d += d1.y >> 16;
    }

    const float sxw = sx_p[0] * sw_p[0];
    const int   ob  = og * OGRP;
    const float b0 = bias[ob + 0], b1 = bias[ob + 1];
    const float b2 = bias[ob + 2], b3 = bias[ob + 3];

    // pass 0 epilogue
    {
        float* op = out + ((b * OC + ob) * HH + h) * WW + w;
        __builtin_nontemporal_store((float)p0a * sxw + b0, op + 0 * HH * WW);
        __builtin_nontemporal_store((float)p0b * sxw + b1, op + 1 * HH * WW);
        __builtin_nontemporal_store((float)p0c * sxw + b2, op + 2 * HH * WW);
        __builtin_nontemporal_store((float)p0d * sxw + b3, op + 3 * HH * WW);
    }
    // pass 1 epilogue (+4 image rows)
    {
        float* op = out + ((b * OC + ob) * HH + (h + 4)) * WW + w;
        __builtin_nontemporal_store((float)p1a * sxw + b0, op + 0 * HH * WW);
        __builtin_nontemporal_store((float)p1b * sxw + b1, op + 1 * HH * WW);
        __builtin_nontemporal_store((float)p1c * sxw + b2, op + 2 * HH * WW);
        __builtin_nontemporal_store((float)p1d * sxw + b3, op + 3 * HH * WW);
    }
}

// ---------------------------------------------------------------------------
// d_in order: x, weight, bias, scale_x, scale_w, lut
// ws layout: T4 (221184 B) | qa padded (405600 B)  -> total 626784 B
// ---------------------------------------------------------------------------
extern "C" void kernel_launch(void* const* d_in, const int* in_sizes, int n_in,
                              void* d_out, int out_size, void* d_ws, size_t ws_size,
                              hipStream_t stream)
{
    const float* x    = (const float*)d_in[0];
    const float* wgt  = (const float*)d_in[1];
    const float* bias = (const float*)d_in[2];
    const float* sx   = (const float*)d_in[3];
    const float* sw   = (const float*)d_in[4];
    const int*   lut  = (const int*)d_in[5];

    char* ws = (char*)d_ws;
    short*         T4 = (short*)ws;                      // 221184 B
    unsigned char* qa = (unsigned char*)(ws + T4_BYTES); // 405600 B

    // prep: 405600 threads covers padded qa (largest job); T4 part is a subset
    prep_kernel<<<(QA_ELEMS + 255) / 256, 256, 0, stream>>>(
        x, wgt, sx, sw, lut, T4, qa);

    // main: 128 site-superblocks x 4 channel-groups = 512 blocks (2/CU)
    conv_kernel<<<(NSITE / (2 * MBLK)) * NGRP, MBLK, 0, stream>>>(
        qa, T4, bias, sx, sw, (float*)d_out);
}

// Round 6
// 74.686 us; speedup vs baseline: 1.0216x; 1.0216x over previous
//
#include <hip/hip_runtime.h>

// Problem constants (from reference setup_inputs)
#define B_    8
#define CIN   3
#define OC    16
#define HH    128
#define WW    128
#define KK    3
#define FF    27              // CIN*KK*KK
#define NSITE (B_*HH*WW)      // 131072 output pixel-sites
#define OGRP  4               // output channels per block
#define NGRP  (OC/OGRP)       // 4 channel groups
#define MBLK  512             // main-kernel block size
#define PH    130             // padded activation plane dim (128 + 1 halo each side)
#define PLANE (PH*PH)         // 16900 bytes per (b,c) plane
#define QA_ELEMS (B_*CIN*PLANE)        // 405600
#define T4_BYTES (NGRP*FF*256*4*2)     // 221184: 4 groups x 27 f x 256 a x 4ch x 2B
#define SLAB_INT4 (FF*256*4*2/16)      // 3456 dwordx4 chunks per 55296B group slab

// ---------------------------------------------------------------------------
// Prep kernel (single launch, no internal deps):
//  (1) qa: padded quantized activations [B][C][130][130]; border = 128 (qx=0).
//      Bit-exact vs reference: IEEE f32 divide + rintf (nearest-even, matches
//      jnp.round) + clip, then +128 bias to unsigned.
//  (2) T4: packed LUT slabs. T4[og][f][a] = 8-byte entry holding the four
//      int16 approx-products for output channels og*4..og*4+3 at activation
//      byte a. row = (a<<8)|iw, val = hi*256 + (lo&255) (fits int16).
// ---------------------------------------------------------------------------
__global__ void prep_kernel(const float* __restrict__ x,
                            const float* __restrict__ wgt,
                            const float* __restrict__ sx_p,
                            const float* __restrict__ sw_p,
                            const int*   __restrict__ lut,
                            short*       __restrict__ T4,
                            unsigned char* __restrict__ qa)
{
    const int i = blockIdx.x * blockDim.x + threadIdx.x;

    if (i < QA_ELEMS) {
        int bc = i / PLANE;            // b*CIN + c
        int p  = i - bc * PLANE;
        int hp = p / PH;               // padded row 0..129
        int wp = p - hp * PH;          // padded col 0..129
        int h  = hp - 1;
        int w  = wp - 1;
        unsigned char v = 128;         // zero-pad => qx=0 => a=128
        if ((unsigned)h < HH && (unsigned)w < WW) {
            float q = rintf(x[(bc * HH + h) * WW + w] / sx_p[0]);
            q = fminf(127.f, fmaxf(-127.f, q));
            v = (unsigned char)((int)q + 128);
        }
        qa[i] = v;
    }

    if (i < NGRP * FF * 256) {
        int og = i / (FF * 256);
        int r  = i - og * (FF * 256);
        int f  = r >> 8;
        int a  = r & 255;
        int vals[4];
        #pragma unroll
        for (int ol = 0; ol < 4; ++ol) {
            int o = og * OGRP + ol;
            float q = rintf(wgt[o * FF + f] / sw_p[0]);
            q = fminf(127.f, fmaxf(-127.f, q));
            int iw  = (int)q + 128;                  // in [1,255]
            int row = (a << 8) | iw;                 // reference idx = ip*256+iw
            int hi  = lut[2 * row];
            int lo  = lut[2 * row + 1] & 255;
            vals[ol] = hi * 256 + lo;                // [-32512, 32767]
        }
        int2 d;
        d.x = (vals[1] << 16) | (vals[0] & 0xffff);  // shorts [ch0, ch1]
        d.y = (vals[3] << 16) | (vals[2] & 0xffff);  // shorts [ch2, ch3]
        *reinterpret_cast<int2*>(T4 + (size_t)i * 4) = d;
    }
}

// ---------------------------------------------------------------------------
// Main kernel: block = (1024 sites, two 512-site passes) x (4 packed channels).
//  - staging: 7-iteration dwordx4 memcpy of the group's 55296B T4 slab
//    (coalesced, L2-resident) -> LDS; TWO passes amortize it.
//  - gather: one ds_read_b64 per feature f (imm offset f*2048) yields all 4
//    channels' int16 values; 27 DS gathers per site.
//  - patches: padded qa -> 27 unconditional global_load_ubyte, imm offsets.
//    Issued per-pass AFTER the barrier: with 16 waves/CU their latency is
//    hidden by TLP (r4 experiment proved pre-issuing them regresses: VMEM
//    queue contention with staging + doubled live VGPRs).
//  - outputs: nontemporal stores (write-once data; keep T4/qa L2-hot).
// 55296B LDS + VGPR<=128 (launch_bounds 512,4) -> 2 blocks/CU, 16 waves/CU.
// Grid 512 = exactly 2 blocks/CU on 256 CUs: single scheduling round.
// ---------------------------------------------------------------------------
__global__ __launch_bounds__(MBLK, 4) void conv_kernel(
    const unsigned char* __restrict__ qa,
    const short* __restrict__ T4,
    const float* __restrict__ bias,
    const float* __restrict__ sx_p,
    const float* __restrict__ sw_p,
    float*       __restrict__ out)
{
    __shared__ int2 colv[FF * 256];   // 55296 B: [f][a] -> 4 packed int16

    const int og  = blockIdx.x & 3;   // output-channel group
    const int sb2 = blockIdx.x >> 2;  // 1024-site superblock

    // Stage the group's packed slab: 3456 x 16B, 512 threads -> <=7 each.
    {
        const int4* __restrict__ src =
            reinterpret_cast<const int4*>(T4 + (size_t)og * FF * 256 * 4);
        int4* dst = reinterpret_cast<int4*>(colv);
        for (int c = threadIdx.x; c < SLAB_INT4; c += MBLK)
            dst[c] = src[c];
    }
    __syncthreads();

    const float sxw = sx_p[0] * sw_p[0];
    const int   ob  = og * OGRP;

    #pragma unroll
    for (int pass = 0; pass < 2; ++pass) {
        const int s  = (sb2 * 2 + pass) * MBLK + threadIdx.x;
        const int b  = s >> 14;
        const int hw = s & 16383;
        const int h  = hw >> 7;
        const int w  = hw & 127;

        // 3x3x3 patch: padded rows h..h+2, cols w..w+2, imm offsets kh*PH+kw.
        int av[FF];
        #pragma unroll
        for (int c = 0; c < CIN; ++c) {
            const unsigned char* __restrict__ bp =
                qa + (b * CIN + c) * PLANE + h * PH + w;
            #pragma unroll
            for (int kh = 0; kh < KK; ++kh)
                #pragma unroll
                for (int kw = 0; kw < KK; ++kw)
                    av[c * 9 + kh * 3 + kw] = bp[kh * PH + kw];
        }

        int acc0 = 0, acc1 = 0, acc2 = 0, acc3 = 0;
        #pragma unroll
        for (int f = 0; f < FF; ++f) {
            int2 d = colv[f * 256 + av[f]];   // ds_read_b64, imm offset f*2048
            acc0 += (short)d.x;               // sext low 16
            acc1 += d.x >> 16;                // arith shift = sext high 16
            acc2 += (short)d.y;
            acc3 += d.y >> 16;
        }

        float* op = out + ((b * OC + ob) * HH + h) * WW + w;
        __builtin_nontemporal_store((float)acc0 * sxw + bias[ob + 0], op + 0 * HH * WW);
        __builtin_nontemporal_store((float)acc1 * sxw + bias[ob + 1], op + 1 * HH * WW);
        __builtin_nontemporal_store((float)acc2 * sxw + bias[ob + 2], op + 2 * HH * WW);
        __builtin_nontemporal_store((float)acc3 * sxw + bias[ob + 3], op + 3 * HH * WW);
    }
}

// ---------------------------------------------------------------------------
// d_in order: x, weight, bias, scale_x, scale_w, lut
// ws layout: T4 (221184 B) | qa padded (405600 B)  -> total 626784 B
// ---------------------------------------------------------------------------
extern "C" void kernel_launch(void* const* d_in, const int* in_sizes, int n_in,
                              void* d_out, int out_size, void* d_ws, size_t ws_size,
                              hipStream_t stream)
{
    const float* x    = (const float*)d_in[0];
    const float* wgt  = (const float*)d_in[1];
    const float* bias = (const float*)d_in[2];
    const float* sx   = (const float*)d_in[3];
    const float* sw   = (const float*)d_in[4];
    const int*   lut  = (const int*)d_in[5];

    char* ws = (char*)d_ws;
    short*         T4 = (short*)ws;                      // 221184 B
    unsigned char* qa = (unsigned char*)(ws + T4_BYTES); // 405600 B

    // prep: 405600 threads covers padded qa (largest job); T4 part is a subset
    prep_kernel<<<(QA_ELEMS + 255) / 256, 256, 0, stream>>>(
        x, wgt, sx, sw, lut, T4, qa);

    // main: 128 site-superblocks x 4 channel-groups = 512 blocks (2/CU)
    conv_kernel<<<(NSITE / (2 * MBLK)) * NGRP, MBLK, 0, stream>>>(
        qa, T4, bias, sx, sw, (float*)d_out);
}